// Round 2
// baseline (797.653 us; speedup 1.0000x reference)
//
#include <hip/hip_runtime.h>
#include <hip/hip_bf16.h>
#include <cstdint>
#include <cstddef>

// Problem constants (HybridMoE): T tokens, H hidden, I intermediate, E experts, top-2.
#define TT 2048
#define HH 2048
#define II 1408
#define EE 8

typedef unsigned short u16;
typedef __attribute__((ext_vector_type(8))) __bf16 bf16x8;   // MFMA A/B operand (4 VGPRs)
typedef __attribute__((ext_vector_type(4))) float f32x4;     // MFMA C/D operand

// ---------- helpers ----------
__device__ __forceinline__ float bf2f(u16 b) {
    return __uint_as_float(((uint32_t)b) << 16);
}
__device__ __forceinline__ u16 f2bf(float x) {   // round-to-nearest-even
    uint32_t u = __float_as_uint(x);
    u += 0x7fffu + ((u >> 16) & 1u);
    return (u16)(u >> 16);
}

// ---------- dtype sniff: decide whether inputs are f32 (flag=1) or bf16 (flag=0) ----------
// Genuine bf16 ~N(0,1): exponent field in ~[100,140]. f32 data read as u16 pairs has
// mantissa-junk halves with uniform exponent fields -> ~40% "weird" of all sampled u16s.
__global__ void k_sniff(const u16* __restrict__ raw, int* __restrict__ flag) {
    __shared__ int cnt;
    if (threadIdx.x == 0) cnt = 0;
    __syncthreads();
    int w = 0;
    for (int i = threadIdx.x; i < 4096; i += 256) {
        u16 x = raw[i];
        if (x & 0x7fff) {
            int ex = (x >> 7) & 0xff;
            if (ex == 0xff || ex < 100 || ex > 140) ++w;
        }
    }
    atomicAdd(&cnt, w);
    __syncthreads();
    if (threadIdx.x == 0) flag[0] = (cnt > 100) ? 1 : 0;
}

// ---------- cast hidden_states to bf16 workspace copy ----------
__global__ void k_cast(const void* __restrict__ src, const int* __restrict__ flag,
                       u16* __restrict__ dst) {
    const int i0 = (blockIdx.x * 256 + threadIdx.x) * 8;
    if (flag[0]) {
        const float* s = (const float*)src;
#pragma unroll
        for (int j = 0; j < 8; ++j) dst[i0 + j] = f2bf(s[i0 + j]);
    } else {
        const u16* s = (const u16*)src;
        *(uint4*)&dst[i0] = *(const uint4*)&s[i0];
    }
}

// ---------- routing: top-2 softmax -> cw[T,E] (fp32) ----------
__global__ void k_routing(const void* __restrict__ logits, const int* __restrict__ flag,
                          float* __restrict__ cw) {
    int t = blockIdx.x * 256 + threadIdx.x;
    if (t >= TT) return;
    const int f = flag[0];
    float v[EE];
#pragma unroll
    for (int e = 0; e < EE; ++e)
        v[e] = f ? ((const float*)logits)[t * EE + e]
                 : bf2f(((const u16*)logits)[t * EE + e]);
    // first-occurrence argmax (matches lax.top_k stable tie-break)
    int i0 = 0; float v0 = v[0];
#pragma unroll
    for (int e = 1; e < EE; ++e) { if (v[e] > v0) { v0 = v[e]; i0 = e; } }
    int i1 = -1; float v1 = -3.4e38f;
#pragma unroll
    for (int e = 0; e < EE; ++e) { if (e != i0 && v[e] > v1) { v1 = v[e]; i1 = e; } }
    float r = __expf(v1 - v0);          // <= 1
    float s = 1.f / (1.f + r);
#pragma unroll
    for (int e = 0; e < EE; ++e)
        cw[t * EE + e] = (e == i0) ? s : ((e == i1) ? r * s : 0.f);
}

// ---------- 2D transpose per expert: src[R,C] (f32 or bf16) -> dst[C,R] (bf16) ----------
__global__ void k_transpose(const void* __restrict__ src, const int* __restrict__ flag,
                            u16* __restrict__ dst, int R, int C) {
    __shared__ u16 tile[32][33];
    const size_t eo = (size_t)blockIdx.z * (size_t)R * (size_t)C;
    const int f = flag[0];
    const int tx = threadIdx.x, ty = threadIdx.y;
    const int c = blockIdx.x * 32 + tx;
    const int r0 = blockIdx.y * 32 + ty;
#pragma unroll
    for (int j = 0; j < 32; j += 8) {
        const size_t idx = eo + (size_t)(r0 + j) * C + c;
        tile[ty + j][tx] = f ? f2bf(((const float*)src)[idx]) : ((const u16*)src)[idx];
    }
    __syncthreads();
    const int rr = blockIdx.y * 32 + tx;   // col in dst
    const int c0 = blockIdx.x * 32 + ty;   // row in dst
#pragma unroll
    for (int j = 0; j < 32; j += 8)
        dst[eo + (size_t)(c0 + j) * R + rr] = tile[tx][ty + j];
}

// Stage a 128x32 bf16 tile (row-major, 32-elem rows) global->LDS, plain vectorized path.
// 256 threads x 2 x 16B. Isolation round: no global_load_lds.
__device__ __forceinline__ void stageP(const u16* __restrict__ g, int stride_elems,
                                       u16* lds, int tid) {
#pragma unroll
    for (int it = 0; it < 2; ++it) {
        const int gr = tid + it * 256;        // 16B granule id, 0..511
        const int row = gr >> 2;              // 0..127
        const int cg = (gr & 3) * 8;          // elem offset in row
        *(uint4*)&lds[row * 32 + cg] = *(const uint4*)&g[(size_t)row * stride_elems + cg];
    }
}

// ---------- GEMM1 (dual): g=hs@Wg[e], u=hs@Wu[e]; act[e,t,i]=bf16(cw*silu(g)*u) ----------
// 128x128 tile, BK=32, 4 waves each 64x64 (4x4 of 16x16x32 MFMA).
__global__ __launch_bounds__(256, 2)
void k_gemm1(const u16* __restrict__ A,    // hs_b [T,H] bf16
             const u16* __restrict__ Wgt,  // [E,I,H] bf16
             const u16* __restrict__ Wut,  // [E,I,H] bf16
             const float* __restrict__ cw, // [T,E]
             u16* __restrict__ act) {      // [E,T,I] bf16
    const int e  = blockIdx.z;
    const int n0 = blockIdx.x * 128;   // i block
    const int m0 = blockIdx.y * 128;   // token block
    const int tid = threadIdx.x;
    const int wave = tid >> 6, lane = tid & 63;
    const int ln = lane & 15, q = lane >> 4;
    const int wr = (wave >> 1) * 64, wc = (wave & 1) * 64;

    __shared__ __align__(16) u16 As[128 * 32];
    __shared__ __align__(16) u16 Bg[128 * 32];
    __shared__ __align__(16) u16 Bu[128 * 32];

    const u16* gA = A + (size_t)m0 * HH;
    const u16* gG = Wgt + ((size_t)e * II + n0) * HH;
    const u16* gU = Wut + ((size_t)e * II + n0) * HH;

    f32x4 accg[4][4], accu[4][4];
#pragma unroll
    for (int mi = 0; mi < 4; ++mi)
#pragma unroll
        for (int ni = 0; ni < 4; ++ni) { accg[mi][ni] = (f32x4)0.f; accu[mi][ni] = (f32x4)0.f; }

    for (int kb = 0; kb < HH; kb += 32) {
        __syncthreads();                      // previous iter's LDS reads done
        stageP(gA + kb, HH, As, tid);
        stageP(gG + kb, HH, Bg, tid);
        stageP(gU + kb, HH, Bu, tid);
        __syncthreads();                      // tiles visible

        bf16x8 af[4];
#pragma unroll
        for (int mi = 0; mi < 4; ++mi)
            af[mi] = *(const bf16x8*)&As[(wr + mi * 16 + ln) * 32 + q * 8];
#pragma unroll
        for (int ni = 0; ni < 4; ++ni) {
            bf16x8 bgf = *(const bf16x8*)&Bg[(wc + ni * 16 + ln) * 32 + q * 8];
            bf16x8 buf = *(const bf16x8*)&Bu[(wc + ni * 16 + ln) * 32 + q * 8];
#pragma unroll
            for (int mi = 0; mi < 4; ++mi) {
                accg[mi][ni] = __builtin_amdgcn_mfma_f32_16x16x32_bf16(af[mi], bgf, accg[mi][ni], 0, 0, 0);
                accu[mi][ni] = __builtin_amdgcn_mfma_f32_16x16x32_bf16(af[mi], buf, accu[mi][ni], 0, 0, 0);
            }
        }
    }

    // epilogue: C/D layout col=lane&15, row=(lane>>4)*4+reg  [m89/m91-verified]
#pragma unroll
    for (int mi = 0; mi < 4; ++mi) {
#pragma unroll
        for (int r = 0; r < 4; ++r) {
            const int t = m0 + wr + mi * 16 + q * 4 + r;
            const float w = cw[t * EE + e];
#pragma unroll
            for (int ni = 0; ni < 4; ++ni) {
                const int i = n0 + wc + ni * 16 + ln;
                const float g = accg[mi][ni][r];
                const float u = accu[mi][ni][r];
                const float y = w * u * g / (1.f + __expf(-g));  // cw * silu(g) * u
                act[((size_t)e * TT + t) * II + i] = f2bf(y);
            }
        }
    }
}

// ---------- GEMM2: out[t,h] = sum_{e,i} act[e,t,i] * Wd[e,i,h]  (K = E*I = 11264) ----------
__global__ __launch_bounds__(256, 2)
void k_gemm2(const u16* __restrict__ act,  // [E,T,I] bf16
             const u16* __restrict__ Wdt,  // [E,H,I] bf16
             const int* __restrict__ flag,
             void* __restrict__ out) {     // [T,H] f32 or bf16 per flag
    const int n0 = blockIdx.x * 128;   // h block
    const int m0 = blockIdx.y * 128;   // t block
    const int tid = threadIdx.x;
    const int wave = tid >> 6, lane = tid & 63;
    const int ln = lane & 15, q = lane >> 4;
    const int wr = (wave >> 1) * 64, wc = (wave & 1) * 64;

    __shared__ __align__(16) u16 As[128 * 32];
    __shared__ __align__(16) u16 Bs[128 * 32];

    f32x4 acc[4][4];
#pragma unroll
    for (int mi = 0; mi < 4; ++mi)
#pragma unroll
        for (int ni = 0; ni < 4; ++ni) acc[mi][ni] = (f32x4)0.f;

    for (int e = 0; e < EE; ++e) {
        const u16* bA = act + ((size_t)e * TT + m0) * II;
        const u16* bB = Wdt + ((size_t)e * HH + n0) * II;
        for (int i0 = 0; i0 < II; i0 += 32) {   // I % 32 == 0: K-tile never straddles experts
            __syncthreads();
            stageP(bA + i0, II, As, tid);
            stageP(bB + i0, II, Bs, tid);
            __syncthreads();

            bf16x8 af[4];
#pragma unroll
            for (int mi = 0; mi < 4; ++mi)
                af[mi] = *(const bf16x8*)&As[(wr + mi * 16 + ln) * 32 + q * 8];
#pragma unroll
            for (int ni = 0; ni < 4; ++ni) {
                bf16x8 bf = *(const bf16x8*)&Bs[(wc + ni * 16 + ln) * 32 + q * 8];
#pragma unroll
                for (int mi = 0; mi < 4; ++mi)
                    acc[mi][ni] = __builtin_amdgcn_mfma_f32_16x16x32_bf16(af[mi], bf, acc[mi][ni], 0, 0, 0);
            }
        }
    }

    const int f = flag[0];
#pragma unroll
    for (int mi = 0; mi < 4; ++mi) {
#pragma unroll
        for (int r = 0; r < 4; ++r) {
            const int t = m0 + wr + mi * 16 + q * 4 + r;
#pragma unroll
            for (int ni = 0; ni < 4; ++ni) {
                const int h = n0 + wc + ni * 16 + ln;
                if (f) ((float*)out)[(size_t)t * HH + h] = acc[mi][ni][r];
                else   ((u16*)out)[(size_t)t * HH + h]   = f2bf(acc[mi][ni][r]);
            }
        }
    }
}

// ---------- launch ----------
extern "C" void kernel_launch(void* const* d_in, const int* in_sizes, int n_in,
                              void* d_out, int out_size, void* d_ws, size_t ws_size,
                              hipStream_t stream) {
    (void)in_sizes; (void)n_in; (void)out_size;
    const void* hs     = d_in[0];   // [T,H]
    const void* logits = d_in[1];   // [T,E]
    const void* Wg     = d_in[2];   // [E,H,I]
    const void* Wu     = d_in[3];   // [E,H,I]
    const void* Wd     = d_in[4];   // [E,I,H]

    char* ws = (char*)d_ws;
    size_t off = 0;
    int*   flag = (int*)(ws + off);  off += 256;
    float* cw   = (float*)(ws + off); off += (size_t)TT * EE * 4;       // 64 KB
    u16*   Wgt  = (u16*)(ws + off);   off += (size_t)EE * II * HH * 2;  // 46 MB  [E,I,H]
    u16*   Wut  = (u16*)(ws + off);   off += (size_t)EE * II * HH * 2;  // 46 MB  [E,I,H]
    u16*   Wdt  = (u16*)(ws + off);   off += (size_t)EE * HH * II * 2;  // 46 MB  [E,H,I]
    u16*   act  = (u16*)(ws + off);   off += (size_t)EE * TT * II * 2;  // 46 MB  [E,T,I]
    u16*   hs_b = (u16*)(ws + off);   off += (size_t)TT * HH * 2;       // 8 MB   [T,H]
    if (ws_size < off) return;  // insufficient workspace: fail loudly via validation

    k_sniff<<<dim3(1), dim3(256), 0, stream>>>((const u16*)hs, flag);
    k_cast<<<dim3(TT * HH / (256 * 8)), dim3(256), 0, stream>>>(hs, flag, hs_b);
    k_routing<<<dim3(TT / 256), dim3(256), 0, stream>>>(logits, flag, cw);
    // Wg [E,H,I] -> Wgt [E,I,H];  Wu likewise;  Wd [E,I,H] -> Wdt [E,H,I]
    k_transpose<<<dim3(II / 32, HH / 32, EE), dim3(32, 8), 0, stream>>>(Wg, flag, Wgt, HH, II);
    k_transpose<<<dim3(II / 32, HH / 32, EE), dim3(32, 8), 0, stream>>>(Wu, flag, Wut, HH, II);
    k_transpose<<<dim3(HH / 32, II / 32, EE), dim3(32, 8), 0, stream>>>(Wd, flag, Wdt, II, HH);
    k_gemm1<<<dim3(II / 128, TT / 128, EE), dim3(256), 0, stream>>>(hs_b, Wgt, Wut, cw, act);
    k_gemm2<<<dim3(HH / 128, TT / 128), dim3(256), 0, stream>>>(act, Wdt, flag, d_out);
}

// Round 3
// 494.327 us; speedup vs baseline: 1.6136x; 1.6136x over previous
//
#include <hip/hip_runtime.h>
#include <hip/hip_bf16.h>
#include <cstdint>
#include <cstddef>

// Problem constants (HybridMoE): T tokens, H hidden, I intermediate, E experts, top-2.
#define TT 2048
#define HH 2048
#define II 1408
#define EE 8
#define MAXROWS 5120   // sum of 128-padded per-expert counts <= 4096 + 8*127

typedef unsigned short u16;
typedef __attribute__((ext_vector_type(8))) __bf16 bf16x8;   // MFMA A/B operand (4 VGPRs)
typedef __attribute__((ext_vector_type(4))) float f32x4;     // MFMA C/D operand

typedef const __attribute__((address_space(1))) uint32_t* gas1_t;
typedef __attribute__((address_space(3))) uint32_t* las3_t;

// ---------- helpers ----------
__device__ __forceinline__ float bf2f(u16 b) {
    return __uint_as_float(((uint32_t)b) << 16);
}
__device__ __forceinline__ u16 f2bf(float x) {   // round-to-nearest-even
    uint32_t u = __float_as_uint(x);
    u += 0x7fffu + ((u >> 16) & 1u);
    return (u16)(u >> 16);
}

// ---------- dtype sniff: inputs f32 (flag=1) or bf16 (flag=0) ----------
__global__ void k_sniff(const u16* __restrict__ raw, int* __restrict__ flag) {
    __shared__ int cnt;
    if (threadIdx.x == 0) cnt = 0;
    __syncthreads();
    int w = 0;
    for (int i = threadIdx.x; i < 4096; i += 256) {
        u16 x = raw[i];
        if (x & 0x7fff) {
            int ex = (x >> 7) & 0xff;
            if (ex == 0xff || ex < 100 || ex > 140) ++w;
        }
    }
    atomicAdd(&cnt, w);
    __syncthreads();
    if (threadIdx.x == 0) flag[0] = (cnt > 100) ? 1 : 0;
}

// ---------- zero: out_acc [T,H] f32 + counts ----------
__global__ void k_zero(float* __restrict__ out_acc, int* __restrict__ counts) {
    const int i0 = (blockIdx.x * 256 + threadIdx.x) * 4;
    *(float4*)&out_acc[i0] = make_float4(0.f, 0.f, 0.f, 0.f);
    if (blockIdx.x == 0 && threadIdx.x < EE) counts[threadIdx.x] = 0;
}

// ---------- routing: top-2 softmax -> per-expert token lists ----------
__global__ void k_routing2(const void* __restrict__ logits, const int* __restrict__ flag,
                           int* __restrict__ counts, int* __restrict__ idx,
                           float* __restrict__ wt) {
    int t = blockIdx.x * 256 + threadIdx.x;
    if (t >= TT) return;
    const int f = flag[0];
    float v[EE];
#pragma unroll
    for (int e = 0; e < EE; ++e)
        v[e] = f ? ((const float*)logits)[t * EE + e]
                 : bf2f(((const u16*)logits)[t * EE + e]);
    int i0 = 0; float v0 = v[0];
#pragma unroll
    for (int e = 1; e < EE; ++e) { if (v[e] > v0) { v0 = v[e]; i0 = e; } }
    int i1 = -1; float v1 = -3.4e38f;
#pragma unroll
    for (int e = 0; e < EE; ++e) { if (e != i0 && v[e] > v1) { v1 = v[e]; i1 = e; } }
    float r = __expf(v1 - v0);          // <= 1
    float s = 1.f / (1.f + r);
    int p0 = atomicAdd(&counts[i0], 1);
    idx[i0 * TT + p0] = t; wt[i0 * TT + p0] = s;
    int p1 = atomicAdd(&counts[i1], 1);
    idx[i1 * TT + p1] = t; wt[i1 * TT + p1] = r * s;
}

// ---------- offsets: meta[e]=row offset of expert e, meta[8+e]=padded count ----------
__global__ void k_offsets(const int* __restrict__ counts, int* __restrict__ meta) {
    if (threadIdx.x == 0 && blockIdx.x == 0) {
        int off = 0;
        for (int e = 0; e < EE; ++e) {
            int c = counts[e];
            int p = (c + 127) & ~127;
            meta[e] = off; meta[8 + e] = p;
            off += p;
        }
    }
}

// ---------- cast hidden_states to bf16 workspace copy ----------
__global__ void k_cast(const void* __restrict__ src, const int* __restrict__ flag,
                       u16* __restrict__ dst) {
    const int i0 = (blockIdx.x * 256 + threadIdx.x) * 8;
    if (flag[0]) {
        const float* s = (const float*)src;
#pragma unroll
        for (int j = 0; j < 8; ++j) dst[i0 + j] = f2bf(s[i0 + j]);
    } else {
        const u16* s = (const u16*)src;
        *(uint4*)&dst[i0] = *(const uint4*)&s[i0];
    }
}

// ---------- vectorized transpose per expert: src[R,C] (f32/bf16) -> dst[C,R] bf16 ----------
// 64x64 tile, 256 threads: float4 loads, ushort4 stores.
__global__ void k_transposeV(const void* __restrict__ src, const int* __restrict__ flag,
                             u16* __restrict__ dst, int R, int C) {
    __shared__ u16 t[64][68];
    const size_t eo = (size_t)blockIdx.z * (size_t)R * (size_t)C;
    const int r0 = blockIdx.y * 64, c0 = blockIdx.x * 64;
    const int tid = threadIdx.x;
    const int f = flag[0];
    {
        const int cg = tid & 15, rr = tid >> 4;    // load cols c0+cg*4..+3
#pragma unroll
        for (int p = 0; p < 4; ++p) {
            const int r = rr + p * 16;
            const size_t base = eo + (size_t)(r0 + r) * C + c0 + cg * 4;
            if (f) {
                const float4 v = *(const float4*)((const float*)src + base);
                t[r][cg * 4 + 0] = f2bf(v.x); t[r][cg * 4 + 1] = f2bf(v.y);
                t[r][cg * 4 + 2] = f2bf(v.z); t[r][cg * 4 + 3] = f2bf(v.w);
            } else {
                const ushort4 v = *(const ushort4*)((const u16*)src + base);
                t[r][cg * 4 + 0] = v.x; t[r][cg * 4 + 1] = v.y;
                t[r][cg * 4 + 2] = v.z; t[r][cg * 4 + 3] = v.w;
            }
        }
    }
    __syncthreads();
    {
        const int rg = tid & 15, cc = tid >> 4;    // store rows (cols of src)
#pragma unroll
        for (int p = 0; p < 4; ++p) {
            const int c = cc + p * 16;
            ushort4 o;
            o.x = t[rg * 4 + 0][c]; o.y = t[rg * 4 + 1][c];
            o.z = t[rg * 4 + 2][c]; o.w = t[rg * 4 + 3][c];
            *(ushort4*)(dst + eo + (size_t)(c0 + c) * R + r0 + rg * 4) = o;
        }
    }
}

// Stage a 128x32 bf16 tile (rows contiguous) global->LDS via global_load_lds width=16.
__device__ __forceinline__ void stage16(const u16* __restrict__ g, int stride_elems,
                                        u16* lds, int wave, int lane) {
    const int sub = lane >> 2;
    const int col = (lane & 3) * 8;
#pragma unroll
    for (int h = 0; h < 2; ++h) {
        const int rbase = wave * 32 + h * 16;
        const u16* ga = g + (size_t)(rbase + sub) * stride_elems + col;
        __builtin_amdgcn_global_load_lds((gas1_t)ga, (las3_t)(lds + rbase * 32), 16, 0, 0);
    }
}

// ---------- GEMM1 sparse (dual): gathered tokens, g/u matmul + silu*w -> act_g ----------
__global__ __launch_bounds__(256, 2)
void k_gemm1s(const u16* __restrict__ hs_b,  // [T,H] bf16
              const u16* __restrict__ Wgt,   // [E,I,H] bf16
              const u16* __restrict__ Wut,   // [E,I,H] bf16
              const int* __restrict__ counts,
              const int* __restrict__ meta,
              const int* __restrict__ idx,
              const float* __restrict__ wt,
              u16* __restrict__ act_g) {     // [MAXROWS, I] bf16
    const int e = blockIdx.z;
    const int cnt = counts[e];
    const int pcnt = meta[8 + e];
    const int m0 = blockIdx.y * 128;
    if (m0 >= pcnt) return;
    const int n0 = blockIdx.x * 128;
    const int off = meta[e];
    const int tid = threadIdx.x;
    const int wave = tid >> 6, lane = tid & 63;
    const int ln = lane & 15, q = lane >> 4;
    const int wr = (wave >> 1) * 64, wc = (wave & 1) * 64;

    __shared__ __align__(16) u16 As[128 * 32];
    __shared__ __align__(16) u16 Bg[128 * 32];
    __shared__ __align__(16) u16 Bu[128 * 32];
    __shared__ int   tokS[128];
    __shared__ float wtS[128];

    if (tid < 128) {
        const int pos = m0 + tid;
        const bool v = pos < cnt;
        tokS[tid] = v ? idx[e * TT + pos] : 0;
        wtS[tid]  = v ? wt[e * TT + pos] : 0.f;
    }
    __syncthreads();

    // per-lane gather pointers for the A-tile (source per-lane is legal; LDS dest is uniform)
    const int sub = lane >> 2, col = (lane & 3) * 8;
    const int r0 = wave * 32 + sub;
    const u16* pA0 = hs_b + (size_t)tokS[r0] * HH + col;
    const u16* pA1 = hs_b + (size_t)tokS[r0 + 16] * HH + col;
    const u16* gG = Wgt + ((size_t)e * II + n0) * HH;
    const u16* gU = Wut + ((size_t)e * II + n0) * HH;

    f32x4 accg[4][4], accu[4][4];
#pragma unroll
    for (int mi = 0; mi < 4; ++mi)
#pragma unroll
        for (int ni = 0; ni < 4; ++ni) { accg[mi][ni] = (f32x4)0.f; accu[mi][ni] = (f32x4)0.f; }

    for (int kb = 0; kb < HH; kb += 32) {
        __syncthreads();
        __builtin_amdgcn_global_load_lds((gas1_t)(pA0 + kb), (las3_t)(As + (wave * 32) * 32), 16, 0, 0);
        __builtin_amdgcn_global_load_lds((gas1_t)(pA1 + kb), (las3_t)(As + (wave * 32 + 16) * 32), 16, 0, 0);
        stage16(gG + kb, HH, Bg, wave, lane);
        stage16(gU + kb, HH, Bu, wave, lane);
        __syncthreads();

        bf16x8 af[4];
#pragma unroll
        for (int mi = 0; mi < 4; ++mi)
            af[mi] = *(const bf16x8*)&As[(wr + mi * 16 + ln) * 32 + q * 8];
#pragma unroll
        for (int ni = 0; ni < 4; ++ni) {
            bf16x8 bgf = *(const bf16x8*)&Bg[(wc + ni * 16 + ln) * 32 + q * 8];
            bf16x8 buf = *(const bf16x8*)&Bu[(wc + ni * 16 + ln) * 32 + q * 8];
#pragma unroll
            for (int mi = 0; mi < 4; ++mi) {
                accg[mi][ni] = __builtin_amdgcn_mfma_f32_16x16x32_bf16(af[mi], bgf, accg[mi][ni], 0, 0, 0);
                accu[mi][ni] = __builtin_amdgcn_mfma_f32_16x16x32_bf16(af[mi], buf, accu[mi][ni], 0, 0, 0);
            }
        }
    }

    // epilogue: C/D layout col=lane&15, row=(lane>>4)*4+reg; pad rows have w=0 -> write 0
#pragma unroll
    for (int mi = 0; mi < 4; ++mi) {
#pragma unroll
        for (int r = 0; r < 4; ++r) {
            const int row = wr + mi * 16 + q * 4 + r;
            const float w = wtS[row];
#pragma unroll
            for (int ni = 0; ni < 4; ++ni) {
                const int i = n0 + wc + ni * 16 + ln;
                const float g = accg[mi][ni][r];
                const float u = accu[mi][ni][r];
                const float y = w * u * g / (1.f + __expf(-g));  // w * silu(g) * u
                act_g[(size_t)(off + m0 + row) * II + i] = f2bf(y);
            }
        }
    }
}

// ---------- GEMM2 sparse: y = act_g[e-rows] @ Wd[e]; scatter-add into out_acc ----------
__global__ __launch_bounds__(256, 2)
void k_gemm2s(const u16* __restrict__ act_g,  // [MAXROWS, I] bf16
              const u16* __restrict__ Wdt,    // [E,H,I] bf16
              const int* __restrict__ counts,
              const int* __restrict__ meta,
              const int* __restrict__ idx,
              float* __restrict__ out_acc) {  // [T,H] f32
    const int e = blockIdx.z;
    const int cnt = counts[e];
    const int pcnt = meta[8 + e];
    const int m0 = blockIdx.y * 128;
    if (m0 >= pcnt) return;
    const int n0 = blockIdx.x * 128;
    const int off = meta[e];
    const int tid = threadIdx.x;
    const int wave = tid >> 6, lane = tid & 63;
    const int ln = lane & 15, q = lane >> 4;
    const int wr = (wave >> 1) * 64, wc = (wave & 1) * 64;

    __shared__ __align__(16) u16 As[128 * 32];
    __shared__ __align__(16) u16 Bs[128 * 32];
    __shared__ int tokS[128];

    if (tid < 128) {
        const int pos = m0 + tid;
        tokS[tid] = (pos < cnt) ? idx[e * TT + pos] : -1;
    }

    const u16* bA = act_g + (size_t)(off + m0) * II;
    const u16* bB = Wdt + ((size_t)e * HH + n0) * II;

    f32x4 acc[4][4];
#pragma unroll
    for (int mi = 0; mi < 4; ++mi)
#pragma unroll
        for (int ni = 0; ni < 4; ++ni) acc[mi][ni] = (f32x4)0.f;

    for (int i0 = 0; i0 < II; i0 += 32) {
        __syncthreads();
        stage16(bA + i0, II, As, wave, lane);
        stage16(bB + i0, II, Bs, wave, lane);
        __syncthreads();

        bf16x8 af[4];
#pragma unroll
        for (int mi = 0; mi < 4; ++mi)
            af[mi] = *(const bf16x8*)&As[(wr + mi * 16 + ln) * 32 + q * 8];
#pragma unroll
        for (int ni = 0; ni < 4; ++ni) {
            bf16x8 bf = *(const bf16x8*)&Bs[(wc + ni * 16 + ln) * 32 + q * 8];
#pragma unroll
            for (int mi = 0; mi < 4; ++mi)
                acc[mi][ni] = __builtin_amdgcn_mfma_f32_16x16x32_bf16(af[mi], bf, acc[mi][ni], 0, 0, 0);
        }
    }

#pragma unroll
    for (int mi = 0; mi < 4; ++mi) {
#pragma unroll
        for (int r = 0; r < 4; ++r) {
            const int row = wr + mi * 16 + q * 4 + r;
            const int t = tokS[row];
            if (t >= 0) {
#pragma unroll
                for (int ni = 0; ni < 4; ++ni) {
                    const int h = n0 + wc + ni * 16 + ln;
                    unsafeAtomicAdd(&out_acc[(size_t)t * HH + h], acc[mi][ni][r]);
                }
            }
        }
    }
}

// ---------- final cast: out_acc f32 -> d_out (f32 or bf16) ----------
__global__ void k_out(const float* __restrict__ out_acc, const int* __restrict__ flag,
                      void* __restrict__ out) {
    const int i0 = (blockIdx.x * 256 + threadIdx.x) * 4;
    const float4 v = *(const float4*)&out_acc[i0];
    if (flag[0]) {
        *(float4*)((float*)out + i0) = v;
    } else {
        u16* o = (u16*)out + i0;
        o[0] = f2bf(v.x); o[1] = f2bf(v.y); o[2] = f2bf(v.z); o[3] = f2bf(v.w);
    }
}

// ---------- launch ----------
extern "C" void kernel_launch(void* const* d_in, const int* in_sizes, int n_in,
                              void* d_out, int out_size, void* d_ws, size_t ws_size,
                              hipStream_t stream) {
    (void)in_sizes; (void)n_in; (void)out_size;
    const void* hs     = d_in[0];   // [T,H]
    const void* logits = d_in[1];   // [T,E]
    const void* Wg     = d_in[2];   // [E,H,I]
    const void* Wu     = d_in[3];   // [E,H,I]
    const void* Wd     = d_in[4];   // [E,I,H]

    char* ws = (char*)d_ws;
    size_t off = 0;
    int*   flag   = (int*)(ws + off);   off += 256;
    int*   counts = (int*)(ws + off);   off += 256;
    int*   meta   = (int*)(ws + off);   off += 256;
    int*   idx    = (int*)(ws + off);   off += (size_t)EE * TT * 4;       // 64 KB
    float* wt     = (float*)(ws + off); off += (size_t)EE * TT * 4;       // 64 KB
    u16*   hs_b   = (u16*)(ws + off);   off += (size_t)TT * HH * 2;       // 8 MB
    u16*   Wgt    = (u16*)(ws + off);   off += (size_t)EE * II * HH * 2;  // 46 MB [E,I,H]
    u16*   Wut    = (u16*)(ws + off);   off += (size_t)EE * II * HH * 2;  // 46 MB [E,I,H]
    u16*   Wdt    = (u16*)(ws + off);   off += (size_t)EE * HH * II * 2;  // 46 MB [E,H,I]
    u16*   act_g  = (u16*)(ws + off);   off += (size_t)MAXROWS * II * 2;  // 14.4 MB
    float* outacc = (float*)(ws + off); off += (size_t)TT * HH * 4;       // 16.8 MB
    if (ws_size < off) return;

    k_sniff<<<dim3(1), dim3(256), 0, stream>>>((const u16*)hs, flag);
    k_zero<<<dim3(TT * HH / (256 * 4)), dim3(256), 0, stream>>>(outacc, counts);
    k_routing2<<<dim3(TT / 256), dim3(256), 0, stream>>>(logits, flag, counts, idx, wt);
    k_offsets<<<dim3(1), dim3(64), 0, stream>>>(counts, meta);
    k_cast<<<dim3(TT * HH / (256 * 8)), dim3(256), 0, stream>>>(hs, flag, hs_b);
    // Wg [E,H,I] -> Wgt [E,I,H];  Wu likewise;  Wd [E,I,H] -> Wdt [E,H,I]
    k_transposeV<<<dim3(II / 64, HH / 64, EE), dim3(256), 0, stream>>>(Wg, flag, Wgt, HH, II);
    k_transposeV<<<dim3(II / 64, HH / 64, EE), dim3(256), 0, stream>>>(Wu, flag, Wut, HH, II);
    k_transposeV<<<dim3(HH / 64, II / 64, EE), dim3(256), 0, stream>>>(Wd, flag, Wdt, II, HH);
    k_gemm1s<<<dim3(II / 128, TT / 128, EE), dim3(256), 0, stream>>>(hs_b, Wgt, Wut, counts, meta, idx, wt, act_g);
    k_gemm2s<<<dim3(HH / 128, TT / 128, EE), dim3(256), 0, stream>>>(act_g, Wdt, counts, meta, idx, outacc);
    k_out<<<dim3(TT * HH / (256 * 4)), dim3(256), 0, stream>>>(outacc, flag, d_out);
}

// Round 4
// 479.644 us; speedup vs baseline: 1.6630x; 1.0306x over previous
//
#include <hip/hip_runtime.h>
#include <hip/hip_bf16.h>
#include <cstdint>
#include <cstddef>

// Problem constants (HybridMoE): T tokens, H hidden, I intermediate, E experts, top-2.
#define TT 2048
#define HH 2048
#define II 1408
#define EE 8
#define MAXROWS 5120   // sum of 128-padded per-expert counts <= 4096 + 8*127

typedef unsigned short u16;
typedef __attribute__((ext_vector_type(8))) __bf16 bf16x8;   // MFMA A/B operand (4 VGPRs)
typedef __attribute__((ext_vector_type(4))) float f32x4;     // MFMA C/D operand

typedef const __attribute__((address_space(1))) uint32_t* gas1_t;
typedef __attribute__((address_space(3))) uint32_t* las3_t;

// ---------- helpers ----------
__device__ __forceinline__ float bf2f(u16 b) {
    return __uint_as_float(((uint32_t)b) << 16);
}
__device__ __forceinline__ u16 f2bf(float x) {   // round-to-nearest-even
    uint32_t u = __float_as_uint(x);
    u += 0x7fffu + ((u >> 16) & 1u);
    return (u16)(u >> 16);
}

// ---------- dtype sniff: inputs f32 (flag=1) or bf16 (flag=0) ----------
__global__ void k_sniff(const u16* __restrict__ raw, int* __restrict__ flag) {
    __shared__ int cnt;
    if (threadIdx.x == 0) cnt = 0;
    __syncthreads();
    int w = 0;
    for (int i = threadIdx.x; i < 4096; i += 256) {
        u16 x = raw[i];
        if (x & 0x7fff) {
            int ex = (x >> 7) & 0xff;
            if (ex == 0xff || ex < 100 || ex > 140) ++w;
        }
    }
    atomicAdd(&cnt, w);
    __syncthreads();
    if (threadIdx.x == 0) flag[0] = (cnt > 100) ? 1 : 0;
}

// ---------- zero: out_acc [T,H] f32 + counts ----------
__global__ void k_zero(float* __restrict__ out_acc, int* __restrict__ counts) {
    const int i0 = (blockIdx.x * 256 + threadIdx.x) * 4;
    *(float4*)&out_acc[i0] = make_float4(0.f, 0.f, 0.f, 0.f);
    if (blockIdx.x == 0 && threadIdx.x < EE) counts[threadIdx.x] = 0;
}

// ---------- routing: top-2 softmax -> per-expert token lists ----------
__global__ void k_routing2(const void* __restrict__ logits, const int* __restrict__ flag,
                           int* __restrict__ counts, int* __restrict__ idx,
                           float* __restrict__ wt) {
    int t = blockIdx.x * 256 + threadIdx.x;
    if (t >= TT) return;
    const int f = flag[0];
    float v[EE];
#pragma unroll
    for (int e = 0; e < EE; ++e)
        v[e] = f ? ((const float*)logits)[t * EE + e]
                 : bf2f(((const u16*)logits)[t * EE + e]);
    int i0 = 0; float v0 = v[0];
#pragma unroll
    for (int e = 1; e < EE; ++e) { if (v[e] > v0) { v0 = v[e]; i0 = e; } }
    int i1 = -1; float v1 = -3.4e38f;
#pragma unroll
    for (int e = 0; e < EE; ++e) { if (e != i0 && v[e] > v1) { v1 = v[e]; i1 = e; } }
    float r = __expf(v1 - v0);          // <= 1
    float s = 1.f / (1.f + r);
    int p0 = atomicAdd(&counts[i0], 1);
    idx[i0 * TT + p0] = t; wt[i0 * TT + p0] = s;
    int p1 = atomicAdd(&counts[i1], 1);
    idx[i1 * TT + p1] = t; wt[i1 * TT + p1] = r * s;
}

// ---------- offsets: meta[e]=row offset of expert e, meta[8+e]=padded count ----------
__global__ void k_offsets(const int* __restrict__ counts, int* __restrict__ meta) {
    if (threadIdx.x == 0 && blockIdx.x == 0) {
        int off = 0;
        for (int e = 0; e < EE; ++e) {
            int c = counts[e];
            int p = (c + 127) & ~127;
            meta[e] = off; meta[8 + e] = p;
            off += p;
        }
    }
}

// ---------- cast hidden_states to bf16 workspace copy ----------
__global__ void k_cast(const void* __restrict__ src, const int* __restrict__ flag,
                       u16* __restrict__ dst) {
    const int i0 = (blockIdx.x * 256 + threadIdx.x) * 8;
    if (flag[0]) {
        const float* s = (const float*)src;
#pragma unroll
        for (int j = 0; j < 8; ++j) dst[i0 + j] = f2bf(s[i0 + j]);
    } else {
        const u16* s = (const u16*)src;
        *(uint4*)&dst[i0] = *(const uint4*)&s[i0];
    }
}

// ---------- vectorized transpose per expert: src[R,C] (f32/bf16) -> dst[C,R] bf16 ----------
// 64x64 tile, 256 threads: float4 loads, ushort4 stores.  (validated R3)
__global__ void k_transposeV(const void* __restrict__ src, const int* __restrict__ flag,
                             u16* __restrict__ dst, int R, int C) {
    __shared__ u16 t[64][68];
    const size_t eo = (size_t)blockIdx.z * (size_t)R * (size_t)C;
    const int r0 = blockIdx.y * 64, c0 = blockIdx.x * 64;
    const int tid = threadIdx.x;
    const int f = flag[0];
    {
        const int cg = tid & 15, rr = tid >> 4;    // load cols c0+cg*4..+3
#pragma unroll
        for (int p = 0; p < 4; ++p) {
            const int r = rr + p * 16;
            const size_t base = eo + (size_t)(r0 + r) * C + c0 + cg * 4;
            if (f) {
                const float4 v = *(const float4*)((const float*)src + base);
                t[r][cg * 4 + 0] = f2bf(v.x); t[r][cg * 4 + 1] = f2bf(v.y);
                t[r][cg * 4 + 2] = f2bf(v.z); t[r][cg * 4 + 3] = f2bf(v.w);
            } else {
                const ushort4 v = *(const ushort4*)((const u16*)src + base);
                t[r][cg * 4 + 0] = v.x; t[r][cg * 4 + 1] = v.y;
                t[r][cg * 4 + 2] = v.z; t[r][cg * 4 + 3] = v.w;
            }
        }
    }
    __syncthreads();
    {
        const int rg = tid & 15, cc = tid >> 4;    // store rows (cols of src)
#pragma unroll
        for (int p = 0; p < 4; ++p) {
            const int c = cc + p * 16;
            ushort4 o;
            o.x = t[rg * 4 + 0][c]; o.y = t[rg * 4 + 1][c];
            o.z = t[rg * 4 + 2][c]; o.w = t[rg * 4 + 3][c];
            *(ushort4*)(dst + eo + (size_t)(c0 + c) * R + r0 + rg * 4) = o;
        }
    }
}

// Stage a 128x32 bf16 tile global->LDS via global_load_lds width=16.  4-wave (256t) version.
__device__ __forceinline__ void stage16(const u16* __restrict__ g, int stride_elems,
                                        u16* lds, int wave, int lane) {
    const int sub = lane >> 2;
    const int col = (lane & 3) * 8;
#pragma unroll
    for (int h = 0; h < 2; ++h) {
        const int rbase = wave * 32 + h * 16;
        const u16* ga = g + (size_t)(rbase + sub) * stride_elems + col;
        __builtin_amdgcn_global_load_lds((gas1_t)ga, (las3_t)(lds + rbase * 32), 16, 0, 0);
    }
}

// ---------- GEMM1 sparse (dual), 512 threads / 8 waves ----------
// grid (e=8, n=11, m=16): linear%8 == e -> all blocks of one expert on one XCD.
__global__ __launch_bounds__(512, 4)
void k_gemm1s(const u16* __restrict__ hs_b,  // [T,H] bf16
              const u16* __restrict__ Wgt,   // [E,I,H] bf16
              const u16* __restrict__ Wut,   // [E,I,H] bf16
              const int* __restrict__ counts,
              const int* __restrict__ meta,
              const int* __restrict__ idx,
              const float* __restrict__ wt,
              u16* __restrict__ act_g) {     // [MAXROWS, I] bf16
    const int e = blockIdx.x;
    const int cnt = counts[e];
    const int pcnt = meta[8 + e];
    const int m0 = blockIdx.z * 128;
    if (m0 >= pcnt) return;
    const int n0 = blockIdx.y * 128;
    const int off = meta[e];
    const int tid = threadIdx.x;
    const int wave = tid >> 6, lane = tid & 63;
    const int ln = lane & 15, q = lane >> 4;
    const int wr = (wave >> 2) * 64;           // 2 m-rows of waves
    const int wc = (wave & 3) * 32;            // 4 n-cols of waves

    __shared__ __align__(16) u16 As[128 * 32];
    __shared__ __align__(16) u16 Bg[128 * 32];
    __shared__ __align__(16) u16 Bu[128 * 32];
    __shared__ int   tokS[128];
    __shared__ float wtS[128];

    if (tid < 128) {
        const int pos = m0 + tid;
        const bool v = pos < cnt;
        tokS[tid] = v ? idx[e * TT + pos] : 0;
        wtS[tid]  = v ? wt[e * TT + pos] : 0.f;
    }
    __syncthreads();

    // staging geometry: 512 threads x 16B = one 128x32 tile per issue
    const int srow = tid >> 2;                 // 0..127
    const int scol = (tid & 3) * 8;            // bf16 elem offset
    const u16* pA = hs_b + (size_t)tokS[srow] * HH + scol;        // gathered token row
    const u16* pG = Wgt + ((size_t)e * II + n0 + srow) * HH + scol;
    const u16* pU = Wut + ((size_t)e * II + n0 + srow) * HH + scol;
    u16* const lA = As + srow * 32 + scol;     // == wave-uniform base + lane*16B
    u16* const lG = Bg + srow * 32 + scol;
    u16* const lU = Bu + srow * 32 + scol;

    f32x4 accg[4][2], accu[4][2];
#pragma unroll
    for (int mi = 0; mi < 4; ++mi)
#pragma unroll
        for (int ni = 0; ni < 2; ++ni) { accg[mi][ni] = (f32x4)0.f; accu[mi][ni] = (f32x4)0.f; }

    for (int kb = 0; kb < HH; kb += 32) {
        __syncthreads();
        __builtin_amdgcn_global_load_lds((gas1_t)(pA + kb), (las3_t)lA, 16, 0, 0);
        __builtin_amdgcn_global_load_lds((gas1_t)(pG + kb), (las3_t)lG, 16, 0, 0);
        __builtin_amdgcn_global_load_lds((gas1_t)(pU + kb), (las3_t)lU, 16, 0, 0);
        __syncthreads();

        bf16x8 af[4];
#pragma unroll
        for (int mi = 0; mi < 4; ++mi)
            af[mi] = *(const bf16x8*)&As[(wr + mi * 16 + ln) * 32 + q * 8];
#pragma unroll
        for (int ni = 0; ni < 2; ++ni) {
            bf16x8 bgf = *(const bf16x8*)&Bg[(wc + ni * 16 + ln) * 32 + q * 8];
            bf16x8 buf = *(const bf16x8*)&Bu[(wc + ni * 16 + ln) * 32 + q * 8];
#pragma unroll
            for (int mi = 0; mi < 4; ++mi) {
                accg[mi][ni] = __builtin_amdgcn_mfma_f32_16x16x32_bf16(af[mi], bgf, accg[mi][ni], 0, 0, 0);
                accu[mi][ni] = __builtin_amdgcn_mfma_f32_16x16x32_bf16(af[mi], buf, accu[mi][ni], 0, 0, 0);
            }
        }
    }

    // epilogue: C/D layout col=lane&15, row=(lane>>4)*4+reg; pad rows have w=0 -> write 0
#pragma unroll
    for (int mi = 0; mi < 4; ++mi) {
#pragma unroll
        for (int r = 0; r < 4; ++r) {
            const int row = wr + mi * 16 + q * 4 + r;
            const float w = wtS[row];
#pragma unroll
            for (int ni = 0; ni < 2; ++ni) {
                const int i = n0 + wc + ni * 16 + ln;
                const float g = accg[mi][ni][r];
                const float u = accu[mi][ni][r];
                const float y = w * u * g / (1.f + __expf(-g));  // w * silu(g) * u
                act_g[(size_t)(off + m0 + row) * II + i] = f2bf(y);
            }
        }
    }
}

// ---------- GEMM2 sparse: y = act_g[e-rows] @ Wd[e]; scatter-add into out_acc ----------
// grid (e=8, h=16, m=16): linear%8 == e for XCD locality.
__global__ __launch_bounds__(256, 2)
void k_gemm2s(const u16* __restrict__ act_g,  // [MAXROWS, I] bf16
              const u16* __restrict__ Wdt,    // [E,H,I] bf16
              const int* __restrict__ counts,
              const int* __restrict__ meta,
              const int* __restrict__ idx,
              float* __restrict__ out_acc) {  // [T,H] f32
    const int e = blockIdx.x;
    const int cnt = counts[e];
    const int pcnt = meta[8 + e];
    const int m0 = blockIdx.z * 128;
    if (m0 >= pcnt) return;
    const int n0 = blockIdx.y * 128;
    const int off = meta[e];
    const int tid = threadIdx.x;
    const int wave = tid >> 6, lane = tid & 63;
    const int ln = lane & 15, q = lane >> 4;
    const int wr = (wave >> 1) * 64, wc = (wave & 1) * 64;

    __shared__ __align__(16) u16 As[128 * 32];
    __shared__ __align__(16) u16 Bs[128 * 32];
    __shared__ int tokS[128];

    if (tid < 128) {
        const int pos = m0 + tid;
        tokS[tid] = (pos < cnt) ? idx[e * TT + pos] : -1;
    }

    const u16* bA = act_g + (size_t)(off + m0) * II;
    const u16* bB = Wdt + ((size_t)e * HH + n0) * II;

    f32x4 acc[4][4];
#pragma unroll
    for (int mi = 0; mi < 4; ++mi)
#pragma unroll
        for (int ni = 0; ni < 4; ++ni) acc[mi][ni] = (f32x4)0.f;

    for (int i0 = 0; i0 < II; i0 += 32) {
        __syncthreads();
        stage16(bA + i0, II, As, wave, lane);
        stage16(bB + i0, II, Bs, wave, lane);
        __syncthreads();

        bf16x8 af[4];
#pragma unroll
        for (int mi = 0; mi < 4; ++mi)
            af[mi] = *(const bf16x8*)&As[(wr + mi * 16 + ln) * 32 + q * 8];
#pragma unroll
        for (int ni = 0; ni < 4; ++ni) {
            bf16x8 bf = *(const bf16x8*)&Bs[(wc + ni * 16 + ln) * 32 + q * 8];
#pragma unroll
            for (int mi = 0; mi < 4; ++mi)
                acc[mi][ni] = __builtin_amdgcn_mfma_f32_16x16x32_bf16(af[mi], bf, acc[mi][ni], 0, 0, 0);
        }
    }

#pragma unroll
    for (int mi = 0; mi < 4; ++mi) {
#pragma unroll
        for (int r = 0; r < 4; ++r) {
            const int row = wr + mi * 16 + q * 4 + r;
            const int t = tokS[row];
            if (t >= 0) {
#pragma unroll
                for (int ni = 0; ni < 4; ++ni) {
                    const int h = n0 + wc + ni * 16 + ln;
                    unsafeAtomicAdd(&out_acc[(size_t)t * HH + h], acc[mi][ni][r]);
                }
            }
        }
    }
}

// ---------- final cast: out_acc f32 -> d_out (f32 or bf16) ----------
__global__ void k_out(const float* __restrict__ out_acc, const int* __restrict__ flag,
                      void* __restrict__ out) {
    const int i0 = (blockIdx.x * 256 + threadIdx.x) * 4;
    const float4 v = *(const float4*)&out_acc[i0];
    if (flag[0]) {
        *(float4*)((float*)out + i0) = v;
    } else {
        u16* o = (u16*)out + i0;
        o[0] = f2bf(v.x); o[1] = f2bf(v.y); o[2] = f2bf(v.z); o[3] = f2bf(v.w);
    }
}

// ---------- launch ----------
extern "C" void kernel_launch(void* const* d_in, const int* in_sizes, int n_in,
                              void* d_out, int out_size, void* d_ws, size_t ws_size,
                              hipStream_t stream) {
    (void)in_sizes; (void)n_in; (void)out_size;
    const void* hs     = d_in[0];   // [T,H]
    const void* logits = d_in[1];   // [T,E]
    const void* Wg     = d_in[2];   // [E,H,I]
    const void* Wu     = d_in[3];   // [E,H,I]
    const void* Wd     = d_in[4];   // [E,I,H]

    char* ws = (char*)d_ws;
    size_t off = 0;
    int*   flag   = (int*)(ws + off);   off += 256;
    int*   counts = (int*)(ws + off);   off += 256;
    int*   meta   = (int*)(ws + off);   off += 256;
    int*   idx    = (int*)(ws + off);   off += (size_t)EE * TT * 4;       // 64 KB
    float* wt     = (float*)(ws + off); off += (size_t)EE * TT * 4;       // 64 KB
    u16*   hs_b   = (u16*)(ws + off);   off += (size_t)TT * HH * 2;       // 8 MB
    u16*   Wgt    = (u16*)(ws + off);   off += (size_t)EE * II * HH * 2;  // 46 MB [E,I,H]
    u16*   Wut    = (u16*)(ws + off);   off += (size_t)EE * II * HH * 2;  // 46 MB [E,I,H]
    u16*   Wdt    = (u16*)(ws + off);   off += (size_t)EE * HH * II * 2;  // 46 MB [E,H,I]
    u16*   act_g  = (u16*)(ws + off);   off += (size_t)MAXROWS * II * 2;  // 14.4 MB
    float* outacc = (float*)(ws + off); off += (size_t)TT * HH * 4;       // 16.8 MB
    if (ws_size < off) return;

    k_sniff<<<dim3(1), dim3(256), 0, stream>>>((const u16*)hs, flag);
    k_zero<<<dim3(TT * HH / (256 * 4)), dim3(256), 0, stream>>>(outacc, counts);
    k_routing2<<<dim3(TT / 256), dim3(256), 0, stream>>>(logits, flag, counts, idx, wt);
    k_offsets<<<dim3(1), dim3(64), 0, stream>>>(counts, meta);
    k_cast<<<dim3(TT * HH / (256 * 8)), dim3(256), 0, stream>>>(hs, flag, hs_b);
    // Wg [E,H,I] -> Wgt [E,I,H];  Wu likewise;  Wd [E,I,H] -> Wdt [E,H,I]
    k_transposeV<<<dim3(II / 64, HH / 64, EE), dim3(256), 0, stream>>>(Wg, flag, Wgt, HH, II);
    k_transposeV<<<dim3(II / 64, HH / 64, EE), dim3(256), 0, stream>>>(Wu, flag, Wut, HH, II);
    k_transposeV<<<dim3(HH / 64, II / 64, EE), dim3(256), 0, stream>>>(Wd, flag, Wdt, II, HH);
    // e in blockIdx.x => blocks of one expert share an XCD (linear%8==e)
    k_gemm1s<<<dim3(EE, II / 128, TT / 128), dim3(512), 0, stream>>>(hs_b, Wgt, Wut, counts, meta, idx, wt, act_g);
    k_gemm2s<<<dim3(EE, HH / 128, TT / 128), dim3(256), 0, stream>>>(act_g, Wdt, counts, meta, idx, outacc);
    k_out<<<dim3(TT * HH / (256 * 4)), dim3(256), 0, stream>>>(outacc, flag, d_out);
}